// Round 2
// baseline (766.283 us; speedup 1.0000x reference)
//
#include <hip/hip_runtime.h>

typedef unsigned short u16;
typedef unsigned int   u32;
typedef __bf16 bf16x8 __attribute__((ext_vector_type(8)));
typedef float  f32x4  __attribute__((ext_vector_type(4)));

// Problem constants: B=64, S=D=DK=DV=512
#define BATCH 64
#define SEQ   512
#define BSS   (64 * 512 * 512)   // 16,777,216 elements per output tensor
#define MTOT  (64 * 512)         // 32768 rows for projections

__device__ __forceinline__ u16 f2bf(float f) {
  u32 u = __builtin_bit_cast(u32, f);
  u += 0x7FFFu + ((u >> 16) & 1u);   // round-to-nearest-even
  return (u16)(u >> 16);
}

__device__ __forceinline__ void gl16(const void* g, void* l) {
  __builtin_amdgcn_global_load_lds(
      (__attribute__((address_space(1))) void*)g,
      (__attribute__((address_space(3))) void*)l,
      16, 0, 0);
}

// ---------------------------------------------------------------------------
// fp32 -> bf16 conversion for sent+pos in one launch, 8 elements/thread
__global__ __launch_bounds__(256) void cvt2_bf16_kernel(
    const float* __restrict__ in0, u16* __restrict__ out0,
    const float* __restrict__ in1, u16* __restrict__ out1, int n8) {
  int i = blockIdx.x * 256 + threadIdx.x;
  const float* in = in0;
  u16* out = out0;
  if (i >= n8) { i -= n8; in = in1; out = out1; }
  const float4* p = reinterpret_cast<const float4*>(in) + (size_t)i * 2;
  float4 x = p[0], y = p[1];
  uint4 r;
  r.x = (u32)f2bf(x.x) | ((u32)f2bf(x.y) << 16);
  r.y = (u32)f2bf(x.z) | ((u32)f2bf(x.w) << 16);
  r.z = (u32)f2bf(y.x) | ((u32)f2bf(y.y) << 16);
  r.w = (u32)f2bf(y.z) | ((u32)f2bf(y.w) << 16);
  reinterpret_cast<uint4*>(out)[i] = r;
}

// pack 5 weight matrices (each 512x512 row-major [out,in]) into bf16 concats
__global__ __launch_bounds__(256) void pack_w_kernel(
    const float* __restrict__ wq, const float* __restrict__ wk,
    const float* __restrict__ wv, const float* __restrict__ wpq,
    const float* __restrict__ wpk, u16* __restrict__ wc1, u16* __restrict__ wc2) {
  int i = blockIdx.x * 256 + threadIdx.x;        // 0 .. 5*262144-1
  int which = i >> 18;
  int off = i & 262143;
  const float* src = which == 0 ? wq : which == 1 ? wk : which == 2 ? wv
                   : which == 3 ? wpq : wpk;
  u16 h = f2bf(src[off]);
  if (which < 3) wc1[(size_t)which * 262144 + off] = h;
  else           wc2[(size_t)(which - 3) * 262144 + off] = h;
}

__global__ __launch_bounds__(256) void pack_bias_kernel(
    const float* __restrict__ bq, const float* __restrict__ bk,
    const float* __restrict__ bv, const float* __restrict__ bpq,
    const float* __restrict__ bpk, float* __restrict__ b1, float* __restrict__ b2) {
  int i = blockIdx.x * 256 + threadIdx.x;        // 0..2559
  if (i < 1536) {
    b1[i] = i < 512 ? bq[i] : i < 1024 ? bk[i - 512] : bv[i - 1024];
  } else {
    int j = i - 1536;
    b2[j] = j < 512 ? bpq[j] : bpk[j - 512];
  }
}

// ---------------------------------------------------------------------------
// ROUND 2: barrier-free, LDS-free NT GEMM. 128(M) x 128(N) tile, K=512.
// 256 threads = 4 waves in 2(M) x 2(N); each wave computes 64x64 via 4x4
// mfma_f32_16x16x32_bf16. A and B fragments are loaded per-lane DIRECTLY
// from global (per-step slices are 8 KB each -> L1/L2-resident; weights are
// re-read by every M-block -> L2-hot). Hand-pipelined 2-deep ping-pong
// (a0/b0 <-> a1/b1): every MFMA cluster consumes registers while the next
// 8 loads are in flight. Zero barriers, zero LDS -> no lockstep, no vmcnt(0)
// drains, no bank conflicts; occupancy granularity 4 waves.
// MODE 0: proj1 -> bf16 +bias, cols [0,1536) route to QU/KU/V
// MODE 1: proj2 -> bf16 +bias, cols [0,1024) route to QU+512/KU+512
// MODE 2: bmm   -> fp32 out, batched over z (att . V^T)
template <int MODE>
__global__ __launch_bounds__(256, 2) void gemm_bfree(
    const u16* __restrict__ A, const u16* __restrict__ Bm,
    u16* __restrict__ U0, u16* __restrict__ U1, u16* __restrict__ U2,
    const float* __restrict__ bias, float* __restrict__ F) {
  const int t = threadIdx.x;
  const int z = blockIdx.z;
  const int m0 = blockIdx.y * 128;
  const int n0 = blockIdx.x * 128;

  const u16* Ab = A + (MODE == 2 ? (size_t)z * 262144 : 0);
  const u16* Bb = Bm + (MODE == 2 ? (size_t)z * 262144 : 0);
  float* Fb = (MODE == 2) ? (F + (size_t)z * 262144) : F;

  const int l = t & 63;
  const int w = t >> 6;            // 0..3
  const int wm = (w & 1) * 64;
  const int wn = (w >> 1) * 64;
  const int fr = l & 15;
  const int fo = (l >> 4) * 8;     // k-fragment element offset (16B granule)

  const u16* gA = Ab + (size_t)(m0 + wm + fr) * 512 + fo;
  const u16* gB = Bb + (size_t)(n0 + wn + fr) * 512 + fo;

  f32x4 acc[4][4];
#pragma unroll
  for (int i = 0; i < 4; ++i)
#pragma unroll
    for (int j = 0; j < 4; ++j) acc[i][j] = (f32x4){0.f, 0.f, 0.f, 0.f};

  bf16x8 a0[4], b0[4], a1[4], b1[4];
#pragma unroll
  for (int i = 0; i < 4; ++i) {
    a0[i] = *reinterpret_cast<const bf16x8*>(gA + (size_t)i * 16 * 512);
    b0[i] = *reinterpret_cast<const bf16x8*>(gB + (size_t)i * 16 * 512);
  }

  for (int k0 = 0; k0 < 512; k0 += 64) {
    const int k1 = k0 + 32;
    const int k2 = (k0 + 64) & 511;   // wrap: last prefetch reloads k=0 (dead)
#pragma unroll
    for (int i = 0; i < 4; ++i) {
      a1[i] = *reinterpret_cast<const bf16x8*>(gA + (size_t)i * 16 * 512 + k1);
      b1[i] = *reinterpret_cast<const bf16x8*>(gB + (size_t)i * 16 * 512 + k1);
    }
#pragma unroll
    for (int mt = 0; mt < 4; ++mt)
#pragma unroll
      for (int nt = 0; nt < 4; ++nt)
        acc[mt][nt] = __builtin_amdgcn_mfma_f32_16x16x32_bf16(
            a0[mt], b0[nt], acc[mt][nt], 0, 0, 0);
#pragma unroll
    for (int i = 0; i < 4; ++i) {
      a0[i] = *reinterpret_cast<const bf16x8*>(gA + (size_t)i * 16 * 512 + k2);
      b0[i] = *reinterpret_cast<const bf16x8*>(gB + (size_t)i * 16 * 512 + k2);
    }
#pragma unroll
    for (int mt = 0; mt < 4; ++mt)
#pragma unroll
      for (int nt = 0; nt < 4; ++nt)
        acc[mt][nt] = __builtin_amdgcn_mfma_f32_16x16x32_bf16(
            a1[mt], b1[nt], acc[mt][nt], 0, 0, 0);
  }

  // C/D layout: col = lane&15, row = (lane>>4)*4 + reg
  const int cr = (l >> 4) * 4;
  const int cc = l & 15;
#pragma unroll
  for (int mt = 0; mt < 4; ++mt) {
#pragma unroll
    for (int nt = 0; nt < 4; ++nt) {
      const int col = n0 + wn + nt * 16 + cc;
#pragma unroll
      for (int r = 0; r < 4; ++r) {
        const int row = m0 + wm + mt * 16 + cr + r;
        float v = acc[mt][nt][r];
        if (MODE == 2) {
          Fb[(size_t)row * 512 + col] = v;
        } else {
          v += bias[col];
          u16 h = f2bf(v);
          const int which = col >> 9, c = col & 511;
          if (MODE == 0) {
            if (which == 0)      U0[(size_t)row * 1024 + c] = h;      // Q
            else if (which == 1) U1[(size_t)row * 1024 + c] = h;      // K
            else                 U2[(size_t)row * 512 + c] = h;       // V
          } else {
            if (which == 0) U0[(size_t)row * 1024 + 512 + c] = h;     // Uq
            else            U1[(size_t)row * 1024 + 512 + c] = h;     // Uk
          }
        }
      }
    }
  }
}

// ---------------------------------------------------------------------------
// Fused score + softmax (unchanged from round 1 — passing at ~98 µs).
// Barrier-free inner K-loop; A staged per 256-K chunk via gl16 with
// pre-swizzled global source; B loaded global->registers.
__global__ __launch_bounds__(512, 4) void score_softmax(
    const u16* __restrict__ QU, const u16* __restrict__ KU,
    const float* __restrict__ bias, float* __restrict__ attF,
    u16* __restrict__ attB) {
  __shared__ u16 lsA[64 * 256];      // 32 KB  Q-chunk (64 rows x 256 K), swizzled
  __shared__ float sred[64 * 8];     // 2 KB   cross-wave reduce

  const int t = threadIdx.x;
  const int b = blockIdx.x;          // batch; 8 rg-blocks of b share XCD b%8
  const int rg = blockIdx.y;
  const int l = t & 63;
  const int w = t >> 6;
  const int wn = w * 64;
  const int fr = l & 15;
  const int fkb = (l >> 4) * 16;     // byte offset of lane's k-fragment
  const int cc = l & 15;
  const int cr = (l >> 4) * 4;
  const int sw = (l & 7) << 4;       // read-side XOR swizzle

  const int browA = b * 512 + rg * 64;

  // A staging: thread t stages 4x16B. LDS dest linear: byte L = t*16 + i*8192.
  // Source column pre-XOR-swizzled so lds[row][x] = A[row][x ^ ((row&7)<<4)].
  const int stg_colb = ((t & 31) << 4) ^ (((t >> 5) & 7) << 4);
  const char* gAc = (const char*)QU + (size_t)(browA + (t >> 5)) * 2048 + stg_colb;

  // B per-lane base: row (b*512 + wn + fr), k-frag (l>>4)*8
  const u16* gK = KU + (size_t)(b * 512 + wn + fr) * 1024 + (l >> 4) * 8;

  float bc[4];
#pragma unroll
  for (int nt = 0; nt < 4; ++nt) bc[nt] = bias[wn + nt * 16 + cc];

  f32x4 acc[4][4];
#pragma unroll
  for (int i = 0; i < 4; ++i)
#pragma unroll
    for (int j = 0; j < 4; ++j) acc[i][j] = (f32x4){0.f, 0.f, 0.f, 0.f};

#pragma unroll
  for (int c = 0; c < 4; ++c) {      // 4 K-chunks of 256
    __syncthreads();                 // protect lsA overwrite
#pragma unroll
    for (int i = 0; i < 4; ++i)
      gl16(gAc + c * 512 + (size_t)i * 16 * 2048,
           (char*)lsA + t * 16 + (size_t)i * 8192);
    __syncthreads();                 // vmcnt(0) drain: A-chunk ready

#pragma unroll 2
    for (int kk = 0; kk < 8; ++kk) { // barrier-free: B from global, A from LDS
      bf16x8 af[4], bfg[4];
#pragma unroll
      for (int nt = 0; nt < 4; ++nt)
        bfg[nt] = *reinterpret_cast<const bf16x8*>(
            gK + (size_t)nt * 16 * 1024 + c * 256 + kk * 32);
#pragma unroll
      for (int mt = 0; mt < 4; ++mt)
        af[mt] = *reinterpret_cast<const bf16x8*>(
            (const char*)lsA + (mt * 16 + fr) * 512 + ((kk * 64 + fkb) ^ sw));
#pragma unroll
      for (int mt = 0; mt < 4; ++mt)
#pragma unroll
        for (int nt = 0; nt < 4; ++nt)
          acc[mt][nt] = __builtin_amdgcn_mfma_f32_16x16x32_bf16(
              af[mt], bfg[nt], acc[mt][nt], 0, 0, 0);
    }
  }

  // scale + bias
#pragma unroll
  for (int mt = 0; mt < 4; ++mt)
#pragma unroll
    for (int nt = 0; nt < 4; ++nt)
#pragma unroll
      for (int r = 0; r < 4; ++r)
        acc[mt][nt][r] = acc[mt][nt][r] * 0.03125f + bc[nt];

  // row max: shfl within 16-lane col groups, LDS across the 8 waves
  float rm[4][4];
#pragma unroll
  for (int mt = 0; mt < 4; ++mt)
#pragma unroll
    for (int r = 0; r < 4; ++r) {
      float m = fmaxf(fmaxf(acc[mt][0][r], acc[mt][1][r]),
                      fmaxf(acc[mt][2][r], acc[mt][3][r]));
#pragma unroll
      for (int s = 1; s < 16; s <<= 1) m = fmaxf(m, __shfl_xor(m, s, 64));
      rm[mt][r] = m;
    }
  if (cc == 0) {
#pragma unroll
    for (int mt = 0; mt < 4; ++mt)
#pragma unroll
      for (int r = 0; r < 4; ++r)
        sred[(mt * 16 + cr + r) * 8 + w] = rm[mt][r];
  }
  __syncthreads();
#pragma unroll
  for (int mt = 0; mt < 4; ++mt)
#pragma unroll
    for (int r = 0; r < 4; ++r) {
      const float* p = &sred[(mt * 16 + cr + r) * 8];
      f32x4 a = *reinterpret_cast<const f32x4*>(p);
      f32x4 c = *reinterpret_cast<const f32x4*>(p + 4);
      rm[mt][r] = fmaxf(fmaxf(fmaxf(a[0], a[1]), fmaxf(a[2], a[3])),
                        fmaxf(fmaxf(c[0], c[1]), fmaxf(c[2], c[3])));
    }
  __syncthreads();

  // exp + row sum
  float rs[4][4];
#pragma unroll
  for (int mt = 0; mt < 4; ++mt)
#pragma unroll
    for (int r = 0; r < 4; ++r) {
      float s = 0.f;
#pragma unroll
      for (int nt = 0; nt < 4; ++nt) {
        float e = __expf(acc[mt][nt][r] - rm[mt][r]);
        acc[mt][nt][r] = e;
        s += e;
      }
#pragma unroll
      for (int sh = 1; sh < 16; sh <<= 1) s += __shfl_xor(s, sh, 64);
      rs[mt][r] = s;
    }
  if (cc == 0) {
#pragma unroll
    for (int mt = 0; mt < 4; ++mt)
#pragma unroll
      for (int r = 0; r < 4; ++r)
        sred[(mt * 16 + cr + r) * 8 + w] = rs[mt][r];
  }
  __syncthreads();
#pragma unroll
  for (int mt = 0; mt < 4; ++mt)
#pragma unroll
    for (int r = 0; r < 4; ++r) {
      const float* p = &sred[(mt * 16 + cr + r) * 8];
      f32x4 a = *reinterpret_cast<const f32x4*>(p);
      f32x4 c = *reinterpret_cast<const f32x4*>(p + 4);
      rs[mt][r] = 1.0f / ((a[0] + a[1]) + (a[2] + a[3]) +
                          (c[0] + c[1]) + (c[2] + c[3]));
    }

  // normalize + write fp32 att (output 0) and bf16 att (bmm input)
  float* aF = attF + (size_t)b * 262144 + (size_t)rg * 64 * 512;
  u16* aB = attB + (size_t)b * 262144 + (size_t)rg * 64 * 512;
#pragma unroll
  for (int mt = 0; mt < 4; ++mt)
#pragma unroll
    for (int nt = 0; nt < 4; ++nt)
#pragma unroll
      for (int r = 0; r < 4; ++r) {
        const size_t idx = (size_t)(mt * 16 + cr + r) * 512 + wn + nt * 16 + cc;
        float a = acc[mt][nt][r] * rs[mt][r];
        aF[idx] = a;
        aB[idx] = f2bf(a);
      }
}

// ---------------------------------------------------------------------------
extern "C" void kernel_launch(void* const* d_in, const int* in_sizes, int n_in,
                              void* d_out, int out_size, void* d_ws,
                              size_t ws_size, hipStream_t stream) {
  const float* sent = (const float*)d_in[0];
  const float* pos  = (const float*)d_in[1];
  // d_in[2] = branch_emb (unused by reference)
  const float* Wq  = (const float*)d_in[3];
  const float* bq  = (const float*)d_in[4];
  const float* Wk  = (const float*)d_in[5];
  const float* bk  = (const float*)d_in[6];
  const float* Wv  = (const float*)d_in[7];
  const float* bv  = (const float*)d_in[8];
  const float* Wpq = (const float*)d_in[9];
  const float* bpq = (const float*)d_in[10];
  const float* Wpk = (const float*)d_in[11];
  const float* bpk = (const float*)d_in[12];
  const float* abias = (const float*)d_in[13];
  float* out = (float*)d_out;

  // ws layout (bytes)
  char* ws = (char*)d_ws;
  u16* Xs   = (u16*)(ws);                    // sent bf16 [32768,512]
  u16* Xp   = (u16*)(ws + 33554432ul);       // pos  bf16
  u16* QU   = (u16*)(ws + 67108864ul);       // [32768,1024] = Q|Uq
  u16* KU   = (u16*)(ws + 134217728ul);      // [32768,1024] = K|Uk
  u16* Vb   = (u16*)(ws + 201326592ul);      // [32768,512]
  u16* attB = (u16*)(ws + 234881024ul);      // [64*512,512] bf16 att
  u16* Wc1  = (u16*)(ws + 268435456ul);      // [1536,512]
  u16* Wc2  = (u16*)(ws + 270008320ul);      // [1024,512]
  float* b1 = (float*)(ws + 271056896ul);
  float* b2 = (float*)(ws + 271063040ul);

  float* attF = out;            // output 0: att_softmax
  float* out2 = out + BSS;      // output 1: bmm result

  cvt2_bf16_kernel<<<16384, 256, 0, stream>>>(sent, Xs, pos, Xp, MTOT * 512 / 8);
  pack_w_kernel<<<5120, 256, 0, stream>>>(Wq, Wk, Wv, Wpq, Wpk, Wc1, Wc2);
  pack_bias_kernel<<<10, 256, 0, stream>>>(bq, bk, bv, bpq, bpk, b1, b2);

  // projections: [32768,512] x [N,512]^T, 128x128 tiles, barrier-free
  gemm_bfree<0><<<dim3(12, 256, 1), 256, 0, stream>>>(Xs, Wc1, QU, KU, Vb, b1, nullptr);
  gemm_bfree<1><<<dim3(8, 256, 1), 256, 0, stream>>>(Xp, Wc2, QU, KU, nullptr, b2, nullptr);

  // fused score + softmax (logits never materialized)
  score_softmax<<<dim3(BATCH, 8, 1), 512, 0, stream>>>(QU, KU, abias, attF, attB);

  // output: per batch att[512,512] x V[512,512]^T
  gemm_bfree<2><<<dim3(4, 4, BATCH), 256, 0, stream>>>(attB, Vb, nullptr, nullptr,
                                                       nullptr, nullptr, out2);

  (void)in_sizes; (void)n_in; (void)out_size; (void)ws_size;
}

// Round 4
// 504.026 us; speedup vs baseline: 1.5203x; 1.5203x over previous
//
#include <hip/hip_runtime.h>

typedef unsigned short u16;
typedef unsigned int   u32;
typedef __bf16 bf16x8 __attribute__((ext_vector_type(8)));
typedef float  f32x4  __attribute__((ext_vector_type(4)));

// Problem constants: B=64, S=D=DK=DV=512
#define BATCH 64
#define SEQ   512
#define BSS   (64 * 512 * 512)   // 16,777,216 elements per output tensor
#define MTOT  (64 * 512)         // 32768 rows for projections

__device__ __forceinline__ u16 f2bf(float f) {
  u32 u = __builtin_bit_cast(u32, f);
  u += 0x7FFFu + ((u >> 16) & 1u);   // round-to-nearest-even
  return (u16)(u >> 16);
}

__device__ __forceinline__ void gl16(const void* g, void* l) {
  __builtin_amdgcn_global_load_lds(
      (__attribute__((address_space(1))) void*)g,
      (__attribute__((address_space(3))) void*)l,
      16, 0, 0);
}

// ---------------------------------------------------------------------------
// fp32 -> bf16 conversion for sent+pos in one launch, 8 elements/thread
__global__ __launch_bounds__(256) void cvt2_bf16_kernel(
    const float* __restrict__ in0, u16* __restrict__ out0,
    const float* __restrict__ in1, u16* __restrict__ out1, int n8) {
  int i = blockIdx.x * 256 + threadIdx.x;
  const float* in = in0;
  u16* out = out0;
  if (i >= n8) { i -= n8; in = in1; out = out1; }
  const float4* p = reinterpret_cast<const float4*>(in) + (size_t)i * 2;
  float4 x = p[0], y = p[1];
  uint4 r;
  r.x = (u32)f2bf(x.x) | ((u32)f2bf(x.y) << 16);
  r.y = (u32)f2bf(x.z) | ((u32)f2bf(x.w) << 16);
  r.z = (u32)f2bf(y.x) | ((u32)f2bf(y.y) << 16);
  r.w = (u32)f2bf(y.z) | ((u32)f2bf(y.w) << 16);
  reinterpret_cast<uint4*>(out)[i] = r;
}

// pack 5 weight matrices (each 512x512 row-major [out,in]) into bf16 concats
__global__ __launch_bounds__(256) void pack_w_kernel(
    const float* __restrict__ wq, const float* __restrict__ wk,
    const float* __restrict__ wv, const float* __restrict__ wpq,
    const float* __restrict__ wpk, u16* __restrict__ wc1, u16* __restrict__ wc2) {
  int i = blockIdx.x * 256 + threadIdx.x;        // 0 .. 5*262144-1
  int which = i >> 18;
  int off = i & 262143;
  const float* src = which == 0 ? wq : which == 1 ? wk : which == 2 ? wv
                   : which == 3 ? wpq : wpk;
  u16 h = f2bf(src[off]);
  if (which < 3) wc1[(size_t)which * 262144 + off] = h;
  else           wc2[(size_t)(which - 3) * 262144 + off] = h;
}

__global__ __launch_bounds__(256) void pack_bias_kernel(
    const float* __restrict__ bq, const float* __restrict__ bk,
    const float* __restrict__ bv, const float* __restrict__ bpq,
    const float* __restrict__ bpk, float* __restrict__ b1, float* __restrict__ b2) {
  int i = blockIdx.x * 256 + threadIdx.x;        // 0..2559
  if (i < 1536) {
    b1[i] = i < 512 ? bq[i] : i < 1024 ? bk[i - 512] : bv[i - 1024];
  } else {
    int j = i - 1536;
    b2[j] = j < 512 ? bpq[j] : bpk[j - 512];
  }
}

// ---------------------------------------------------------------------------
// ROUND 4 (= round 3 design, grid-bug fixed): LDS-staged NT GEMM,
// 256(M) x 128(N) tile, K=512, BK=32, DOUBLE-BUFFERED 2-phase:
// STAGE(next buf) issued before ds_read+MFMA of current; single barrier/iter
// so the 24KB stage is in flight under the whole compute phase. 512 threads
// = 8 waves 4(M)x2(N), wave = 64x64 via 4x4 mfma_f32_16x16x32_bf16.
//
// LDS layout (conflict-free, fed by global_load_lds with PRE-SWIZZLED global
// source — dest stays lane-linear per m104/m173): row-pairs packed in 128B
// superrows, slot s = ((g<<1)|(row&1)) ^ (pr&7), pr=row>>1, g=16B k-granule.
// Stage->read is a verified involution; fragment ds_read_b128 spreads evenly
// over all 8 bank-quads. Staging coalescing: 16x64B runs/wave.
//
// XCD-contiguous block remap: all grids %8==0; blocks sharing an A-panel
// run consecutively on one XCD -> panel lives in one L2.
//
// MODE 0: proj1 -> bf16 +bias, cols [0,1536) route to QU/KU/V
// MODE 1: proj2 -> bf16 +bias, cols [0,1024) route to QU+512/KU+512
// MODE 2: bmm   -> fp32 out, batched over z (att . V^T)
//         grid MUST be dim3(4,2,BATCH): n-blocks=512/128, m-blocks=512/256.
//         (round 3 crash: dim3(2,4,..) sent m0 to 768 -> OOB writes)
template <int MODE>
__global__ __launch_bounds__(512, 4) void gemm_db(
    const u16* __restrict__ A, const u16* __restrict__ Bm,
    u16* __restrict__ U0, u16* __restrict__ U1, u16* __restrict__ U2,
    const float* __restrict__ bias, float* __restrict__ F) {
  __shared__ u16 ls[2 * 12288];   // 2 x (A 16KB + B 8KB) = 48 KB

  const int t = threadIdx.x;

  // --- bijective XCD-contiguous remap (nwg % 8 == 0 for all grids) ---
  const int gx = gridDim.x, gy = gridDim.y;
  int id = (blockIdx.z * gy + blockIdx.y) * gx + blockIdx.x;
  const int q = (gx * gy * gridDim.z) >> 3;
  id = (id & 7) * q + (id >> 3);
  const int bx = id % gx;
  const int rem = id / gx;
  const int by = rem % gy;
  const int z = rem / gy;

  const int m0 = by * 256;
  const int n0 = bx * 128;
  const int K = 512;

  const u16* Ab = A + (MODE == 2 ? (size_t)z * 262144 : 0);
  const u16* Bb = Bm + (MODE == 2 ? (size_t)z * 262144 : 0);
  float* Fb = (MODE == 2) ? (F + (size_t)z * 262144) : F;

  // --- staging source (pre-swizzled): thread t -> LDS granule t (+chunk) ---
  // granule G: pr = G>>3, s = G&7; content u = s ^ (pr&7);
  // row = 2*pr + (u&1), k-granule g = u>>1.
  const int u = (t & 7) ^ ((t >> 3) & 7);
  const int srow = 2 * (t >> 3) + (u & 1);      // 0..127
  const int scol = (u >> 1) * 8;                // 0..24 elements
  const u16* gA = Ab + (size_t)(m0 + srow) * K + scol;   // +128 rows for chunk 2
  const u16* gB = Bb + (size_t)(n0 + srow) * K + scol;

  const int l = t & 63;
  const int w = t >> 6;
  const int wm = (w & 3) * 64;      // 0..192
  const int wn = (w >> 2) * 64;     // 0..64
  const int fr = l & 15;

  // fragment read offsets: byte = (row&~1)*64 + sOff, sOff lane-constant
  const int sOff = ((2 * (l >> 4) + (fr & 1)) ^ (fr >> 1)) << 4;
  const int aoffB = (((wm + fr) & ~1) << 6) + sOff;           // A region
  const int boffB = 16384 + (((wn + fr) & ~1) << 6) + sOff;   // B region

  f32x4 acc[4][4];
#pragma unroll
  for (int i = 0; i < 4; ++i)
#pragma unroll
    for (int j = 0; j < 4; ++j) acc[i][j] = (f32x4){0.f, 0.f, 0.f, 0.f};

  // prologue: stage tile 0 into buffer 0
  {
    char* Ld = (char*)ls + t * 16;
    gl16(gA, Ld);
    gl16(gA + (size_t)128 * K, Ld + 8192);
    gl16(gB, Ld + 16384);
  }
  __syncthreads();

  int cur = 0;
  for (int it = 0; it < 16; ++it) {
    if (it < 15) {                     // stage next tile into other buffer
      const int k0 = (it + 1) * 32;
      char* Ld = (char*)ls + (cur ^ 1) * 24576 + t * 16;
      gl16(gA + k0, Ld);
      gl16(gA + (size_t)128 * K + k0, Ld + 8192);
      gl16(gB + k0, Ld + 16384);
    }
    const char* Lc = (const char*)ls + cur * 24576;
    bf16x8 af[4], bfv[4];
#pragma unroll
    for (int mt = 0; mt < 4; ++mt)
      af[mt] = *reinterpret_cast<const bf16x8*>(Lc + aoffB + mt * 1024);
#pragma unroll
    for (int nt = 0; nt < 4; ++nt)
      bfv[nt] = *reinterpret_cast<const bf16x8*>(Lc + boffB + nt * 1024);
#pragma unroll
    for (int mt = 0; mt < 4; ++mt)
#pragma unroll
      for (int nt = 0; nt < 4; ++nt)
        acc[mt][nt] = __builtin_amdgcn_mfma_f32_16x16x32_bf16(
            af[mt], bfv[nt], acc[mt][nt], 0, 0, 0);
    __syncthreads();                   // drains stage (in flight all compute)
    cur ^= 1;
  }

  // C/D layout: col = lane&15, row = (lane>>4)*4 + reg
  const int cr = (l >> 4) * 4;
  const int cc = l & 15;
#pragma unroll
  for (int mt = 0; mt < 4; ++mt) {
#pragma unroll
    for (int nt = 0; nt < 4; ++nt) {
      const int col = n0 + wn + nt * 16 + cc;
#pragma unroll
      for (int r = 0; r < 4; ++r) {
        const int row = m0 + wm + mt * 16 + cr + r;
        float v = acc[mt][nt][r];
        if (MODE == 2) {
          Fb[(size_t)row * 512 + col] = v;
        } else {
          v += bias[col];
          u16 h = f2bf(v);
          const int which = col >> 9, c = col & 511;
          if (MODE == 0) {
            if (which == 0)      U0[(size_t)row * 1024 + c] = h;      // Q
            else if (which == 1) U1[(size_t)row * 1024 + c] = h;      // K
            else                 U2[(size_t)row * 512 + c] = h;       // V
          } else {
            if (which == 0) U0[(size_t)row * 1024 + 512 + c] = h;     // Uq
            else            U1[(size_t)row * 1024 + 512 + c] = h;     // Uk
          }
        }
      }
    }
  }
}

// ---------------------------------------------------------------------------
// Fused score + softmax (unchanged — known-good at ~98 µs).
// Barrier-free inner K-loop; A staged per 256-K chunk via gl16 with
// pre-swizzled global source; B loaded global->registers.
__global__ __launch_bounds__(512, 4) void score_softmax(
    const u16* __restrict__ QU, const u16* __restrict__ KU,
    const float* __restrict__ bias, float* __restrict__ attF,
    u16* __restrict__ attB) {
  __shared__ u16 lsA[64 * 256];      // 32 KB  Q-chunk (64 rows x 256 K), swizzled
  __shared__ float sred[64 * 8];     // 2 KB   cross-wave reduce

  const int t = threadIdx.x;
  const int b = blockIdx.x;          // batch; 8 rg-blocks of b share XCD b%8
  const int rg = blockIdx.y;
  const int l = t & 63;
  const int w = t >> 6;
  const int wn = w * 64;
  const int fr = l & 15;
  const int fkb = (l >> 4) * 16;     // byte offset of lane's k-fragment
  const int cc = l & 15;
  const int cr = (l >> 4) * 4;
  const int sw = (l & 7) << 4;       // read-side XOR swizzle

  const int browA = b * 512 + rg * 64;

  // A staging: thread t stages 4x16B. LDS dest linear: byte L = t*16 + i*8192.
  // Source column pre-XOR-swizzled so lds[row][x] = A[row][x ^ ((row&7)<<4)].
  const int stg_colb = ((t & 31) << 4) ^ (((t >> 5) & 7) << 4);
  const char* gAc = (const char*)QU + (size_t)(browA + (t >> 5)) * 2048 + stg_colb;

  // B per-lane base: row (b*512 + wn + fr), k-frag (l>>4)*8
  const u16* gK = KU + (size_t)(b * 512 + wn + fr) * 1024 + (l >> 4) * 8;

  float bc[4];
#pragma unroll
  for (int nt = 0; nt < 4; ++nt) bc[nt] = bias[wn + nt * 16 + cc];

  f32x4 acc[4][4];
#pragma unroll
  for (int i = 0; i < 4; ++i)
#pragma unroll
    for (int j = 0; j < 4; ++j) acc[i][j] = (f32x4){0.f, 0.f, 0.f, 0.f};

#pragma unroll
  for (int c = 0; c < 4; ++c) {      // 4 K-chunks of 256
    __syncthreads();                 // protect lsA overwrite
#pragma unroll
    for (int i = 0; i < 4; ++i)
      gl16(gAc + c * 512 + (size_t)i * 16 * 2048,
           (char*)lsA + t * 16 + (size_t)i * 8192);
    __syncthreads();                 // vmcnt(0) drain: A-chunk ready

#pragma unroll 2
    for (int kk = 0; kk < 8; ++kk) { // barrier-free: B from global, A from LDS
      bf16x8 af[4], bfg[4];
#pragma unroll
      for (int nt = 0; nt < 4; ++nt)
        bfg[nt] = *reinterpret_cast<const bf16x8*>(
            gK + (size_t)nt * 16 * 1024 + c * 256 + kk * 32);
#pragma unroll
      for (int mt = 0; mt < 4; ++mt)
        af[mt] = *reinterpret_cast<const bf16x8*>(
            (const char*)lsA + (mt * 16 + fr) * 512 + ((kk * 64 + fkb) ^ sw));
#pragma unroll
      for (int mt = 0; mt < 4; ++mt)
#pragma unroll
        for (int nt = 0; nt < 4; ++nt)
          acc[mt][nt] = __builtin_amdgcn_mfma_f32_16x16x32_bf16(
              af[mt], bfg[nt], acc[mt][nt], 0, 0, 0);
    }
  }

  // scale + bias
#pragma unroll
  for (int mt = 0; mt < 4; ++mt)
#pragma unroll
    for (int nt = 0; nt < 4; ++nt)
#pragma unroll
      for (int r = 0; r < 4; ++r)
        acc[mt][nt][r] = acc[mt][nt][r] * 0.03125f + bc[nt];

  // row max: shfl within 16-lane col groups, LDS across the 8 waves
  float rm[4][4];
#pragma unroll
  for (int mt = 0; mt < 4; ++mt)
#pragma unroll
    for (int r = 0; r < 4; ++r) {
      float m = fmaxf(fmaxf(acc[mt][0][r], acc[mt][1][r]),
                      fmaxf(acc[mt][2][r], acc[mt][3][r]));
#pragma unroll
      for (int s = 1; s < 16; s <<= 1) m = fmaxf(m, __shfl_xor(m, s, 64));
      rm[mt][r] = m;
    }
  if (cc == 0) {
#pragma unroll
    for (int mt = 0; mt < 4; ++mt)
#pragma unroll
      for (int r = 0; r < 4; ++r)
        sred[(mt * 16 + cr + r) * 8 + w] = rm[mt][r];
  }
  __syncthreads();
#pragma unroll
  for (int mt = 0; mt < 4; ++mt)
#pragma unroll
    for (int r = 0; r < 4; ++r) {
      const float* p = &sred[(mt * 16 + cr + r) * 8];
      f32x4 a = *reinterpret_cast<const f32x4*>(p);
      f32x4 c = *reinterpret_cast<const f32x4*>(p + 4);
      rm[mt][r] = fmaxf(fmaxf(fmaxf(a[0], a[1]), fmaxf(a[2], a[3])),
                        fmaxf(fmaxf(c[0], c[1]), fmaxf(c[2], c[3])));
    }
  __syncthreads();

  // exp + row sum
  float rs[4][4];
#pragma unroll
  for (int mt = 0; mt < 4; ++mt)
#pragma unroll
    for (int r = 0; r < 4; ++r) {
      float s = 0.f;
#pragma unroll
      for (int nt = 0; nt < 4; ++nt) {
        float e = __expf(acc[mt][nt][r] - rm[mt][r]);
        acc[mt][nt][r] = e;
        s += e;
      }
#pragma unroll
      for (int sh = 1; sh < 16; sh <<= 1) s += __shfl_xor(s, sh, 64);
      rs[mt][r] = s;
    }
  if (cc == 0) {
#pragma unroll
    for (int mt = 0; mt < 4; ++mt)
#pragma unroll
      for (int r = 0; r < 4; ++r)
        sred[(mt * 16 + cr + r) * 8 + w] = rs[mt][r];
  }
  __syncthreads();
#pragma unroll
  for (int mt = 0; mt < 4; ++mt)
#pragma unroll
    for (int r = 0; r < 4; ++r) {
      const float* p = &sred[(mt * 16 + cr + r) * 8];
      f32x4 a = *reinterpret_cast<const f32x4*>(p);
      f32x4 c = *reinterpret_cast<const f32x4*>(p + 4);
      rs[mt][r] = 1.0f / ((a[0] + a[1]) + (a[2] + a[3]) +
                          (c[0] + c[1]) + (c[2] + c[3]));
    }

  // normalize + write fp32 att (output 0) and bf16 att (bmm input)
  float* aF = attF + (size_t)b * 262144 + (size_t)rg * 64 * 512;
  u16* aB = attB + (size_t)b * 262144 + (size_t)rg * 64 * 512;
#pragma unroll
  for (int mt = 0; mt < 4; ++mt)
#pragma unroll
    for (int nt = 0; nt < 4; ++nt)
#pragma unroll
      for (int r = 0; r < 4; ++r) {
        const size_t idx = (size_t)(mt * 16 + cr + r) * 512 + wn + nt * 16 + cc;
        float a = acc[mt][nt][r] * rs[mt][r];
        aF[idx] = a;
        aB[idx] = f2bf(a);
      }
}

// ---------------------------------------------------------------------------
extern "C" void kernel_launch(void* const* d_in, const int* in_sizes, int n_in,
                              void* d_out, int out_size, void* d_ws,
                              size_t ws_size, hipStream_t stream) {
  const float* sent = (const float*)d_in[0];
  const float* pos  = (const float*)d_in[1];
  // d_in[2] = branch_emb (unused by reference)
  const float* Wq  = (const float*)d_in[3];
  const float* bq  = (const float*)d_in[4];
  const float* Wk  = (const float*)d_in[5];
  const float* bk  = (const float*)d_in[6];
  const float* Wv  = (const float*)d_in[7];
  const float* bv  = (const float*)d_in[8];
  const float* Wpq = (const float*)d_in[9];
  const float* bpq = (const float*)d_in[10];
  const float* Wpk = (const float*)d_in[11];
  const float* bpk = (const float*)d_in[12];
  const float* abias = (const float*)d_in[13];
  float* out = (float*)d_out;

  // ws layout (bytes)
  char* ws = (char*)d_ws;
  u16* Xs   = (u16*)(ws);                    // sent bf16 [32768,512]
  u16* Xp   = (u16*)(ws + 33554432ul);       // pos  bf16
  u16* QU   = (u16*)(ws + 67108864ul);       // [32768,1024] = Q|Uq
  u16* KU   = (u16*)(ws + 134217728ul);      // [32768,1024] = K|Uk
  u16* Vb   = (u16*)(ws + 201326592ul);      // [32768,512]
  u16* attB = (u16*)(ws + 234881024ul);      // [64*512,512] bf16 att
  u16* Wc1  = (u16*)(ws + 268435456ul);      // [1536,512]
  u16* Wc2  = (u16*)(ws + 270008320ul);      // [1024,512]
  float* b1 = (float*)(ws + 271056896ul);
  float* b2 = (float*)(ws + 271063040ul);

  float* attF = out;            // output 0: att_softmax
  float* out2 = out + BSS;      // output 1: bmm result

  cvt2_bf16_kernel<<<16384, 256, 0, stream>>>(sent, Xs, pos, Xp, MTOT * 512 / 8);
  pack_w_kernel<<<5120, 256, 0, stream>>>(Wq, Wk, Wv, Wpq, Wpk, Wc1, Wc2);
  pack_bias_kernel<<<10, 256, 0, stream>>>(bq, bk, bv, bpq, bpk, b1, b2);

  // projections: [32768,512] x [N,512]^T, 256x128 tiles, double-buffered
  gemm_db<0><<<dim3(12, 128, 1), 512, 0, stream>>>(Xs, Wc1, QU, KU, Vb, b1, nullptr);
  gemm_db<1><<<dim3(8, 128, 1), 512, 0, stream>>>(Xp, Wc2, QU, KU, nullptr, b2, nullptr);

  // fused score + softmax (logits never materialized)
  score_softmax<<<dim3(BATCH, 8, 1), 512, 0, stream>>>(QU, KU, abias, attF, attB);

  // output: per batch att[512,512] x V[512,512]^T
  // grid = (N/128, M/256, BATCH) = (4, 2, 64)  [round-3 crash was (2,4,..)]
  gemm_db<2><<<dim3(4, 2, BATCH), 512, 0, stream>>>(attB, Vb, nullptr, nullptr,
                                                    nullptr, nullptr, out2);

  (void)in_sizes; (void)n_in; (void)out_size; (void)ws_size;
}